// Round 1
// baseline (828.029 us; speedup 1.0000x reference)
//
#include <hip/hip_runtime.h>
#include <cstddef>

// ---------- helpers ----------
typedef __bf16 bf16x8 __attribute__((ext_vector_type(8)));
typedef float  floatx4 __attribute__((ext_vector_type(4)));

static __device__ __forceinline__ unsigned short f2bf(float f) {
    unsigned int u = __float_as_uint(f);
    u = u + 0x7fff + ((u >> 16) & 1);   // round-to-nearest-even
    return (unsigned short)(u >> 16);
}

// ---------- kernel 1: masked gather-sum -> x (bf16, concat order applied) ----------
// grid = B * 4 blocks, block = 256 threads.
// piece = blockIdx & 3 : half = piece>>1 (which 2048-col half of x),
//                        sub  = piece&1 (which 1024-col chunk of that half).
// Each block accumulates 32 embedding rows over 1024 contiguous cols.
__global__ __launch_bounds__(256) void nnue_gather(
    const int* __restrict__ white, const int* __restrict__ black,
    const int* __restrict__ stm, const float* __restrict__ emb,
    unsigned short* __restrict__ x)
{
    const int blk   = blockIdx.x;
    const int b     = blk >> 2;
    const int piece = blk & 3;
    const int half  = piece >> 1;
    const int sub   = piece & 1;
    const int t     = threadIdx.x;

    __shared__ int sIdx[32];

    const int stm_b = stm[b];
    // half 0 holds (stm? white : black); half 1 holds (stm? black : white)
    const bool use_white = ((stm_b != 0) != (half != 0));
    const int* lst = use_white ? (white + b * 32) : (black + b * 32);
    if (t < 32) sIdx[t] = lst[t];
    __syncthreads();

    const int c = sub * 1024 + t * 4;   // column within the 2048-dim embedding
    float ax = 0.f, ay = 0.f, az = 0.f, aw = 0.f;
#pragma unroll
    for (int l = 0; l < 32; ++l) {
        const int idx = sIdx[l];
        const float4 v = *reinterpret_cast<const float4*>(emb + (size_t)idx * 2048 + c);
        const float m = (idx != 0) ? 1.0f : 0.0f;   // index 0 = padding
        ax += v.x * m; ay += v.y * m; az += v.z * m; aw += v.w * m;
    }
    ushort4 o;
    o.x = f2bf(ax); o.y = f2bf(ay); o.z = f2bf(az); o.w = f2bf(aw);
    *reinterpret_cast<ushort4*>(x + (size_t)b * 4096 + half * 2048 + c) = o;
}

// ---------- kernel 2: W1 fp32 -> bf16 ----------
__global__ __launch_bounds__(256) void nnue_convw1(
    const float* __restrict__ W1, unsigned short* __restrict__ W1b)
{
    const int i = (blockIdx.x * 256 + threadIdx.x) * 4;   // 128*4096 / 4 = 131072 threads
    const float4 v = *reinterpret_cast<const float4*>(W1 + i);
    ushort4 o;
    o.x = f2bf(v.x); o.y = f2bf(v.y); o.z = f2bf(v.z); o.w = f2bf(v.w);
    *reinterpret_cast<ushort4*>(W1b + i) = o;
}

// ---------- kernel 3: fused MLP:  out = relu(x @ W1^T + b1) @ W2^T + b2 ----------
// M=4096, N=128, K=4096.  BM=64, BN=128, BK=64. grid=64 blocks, 256 thr (4 waves).
// Wave w computes rows [w*16, w*16+16) x all 128 cols: 8 MFMA 16x16x32 frags.
#define LDSTRIDE 72   // 64 + 8 bf16 pad: row shift = 4 banks, 2-way alias (free)
__global__ __launch_bounds__(256) void nnue_mlp(
    const unsigned short* __restrict__ x,   // [4096][4096] bf16
    const unsigned short* __restrict__ w1,  // [128][4096]  bf16
    const float* __restrict__ b1, const float* __restrict__ W2,
    const float* __restrict__ b2, float* __restrict__ out)
{
    __shared__ unsigned short As[64 * LDSTRIDE];
    __shared__ unsigned short Bs[128 * LDSTRIDE];

    const int t    = threadIdx.x;
    const int wid  = t >> 6;
    const int lane = t & 63;
    const int quad = lane >> 4;
    const int l16  = lane & 15;
    const int r0   = blockIdx.x * 64;

    floatx4 acc[8];
#pragma unroll
    for (int i = 0; i < 8; ++i) acc[i] = (floatx4){0.f, 0.f, 0.f, 0.f};

    for (int kc = 0; kc < 4096; kc += 64) {
        __syncthreads();
        // stage A: 64 rows x 64 cols bf16 = 512 x 16B chunks
#pragma unroll
        for (int i = 0; i < 2; ++i) {
            const int c = t + i * 256;
            const int row = c >> 3, cc = c & 7;
            const uint4 v = *reinterpret_cast<const uint4*>(
                x + (size_t)(r0 + row) * 4096 + kc + cc * 8);
            *reinterpret_cast<uint4*>(As + row * LDSTRIDE + cc * 8) = v;
        }
        // stage B (W1): 128 rows x 64 cols = 1024 x 16B chunks
#pragma unroll
        for (int i = 0; i < 4; ++i) {
            const int c = t + i * 256;
            const int row = c >> 3, cc = c & 7;
            const uint4 v = *reinterpret_cast<const uint4*>(
                w1 + (size_t)row * 4096 + kc + cc * 8);
            *reinterpret_cast<uint4*>(Bs + row * LDSTRIDE + cc * 8) = v;
        }
        __syncthreads();
#pragma unroll
        for (int kk = 0; kk < 64; kk += 32) {
            // A frag: A[m = l16][k = kk + quad*8 + j]
            const bf16x8 a = *reinterpret_cast<const bf16x8*>(
                As + (wid * 16 + l16) * LDSTRIDE + kk + quad * 8);
#pragma unroll
            for (int ni = 0; ni < 8; ++ni) {
                // B frag: B[k][n = ni*16 + l16] = W1[n][k]
                const bf16x8 bb = *reinterpret_cast<const bf16x8*>(
                    Bs + (ni * 16 + l16) * LDSTRIDE + kk + quad * 8);
                acc[ni] = __builtin_amdgcn_mfma_f32_16x16x32_bf16(a, bb, acc[ni], 0, 0, 0);
            }
        }
    }

    // epilogue: h = relu(acc + b1); s = h . W2 ; out = s + b2
    const float b2v = b2[0];
    float s[4] = {0.f, 0.f, 0.f, 0.f};
#pragma unroll
    for (int ni = 0; ni < 8; ++ni) {
        const int col = ni * 16 + l16;
        const float bias = b1[col];
        const float w2v  = W2[col];
#pragma unroll
        for (int r = 0; r < 4; ++r) {
            float h = acc[ni][r] + bias;
            h = (h > 0.f) ? h : 0.f;
            s[r] += h * w2v;
        }
    }
    // reduce over the 16 cols held by lanes sharing this quad
#pragma unroll
    for (int r = 0; r < 4; ++r) {
#pragma unroll
        for (int m = 1; m < 16; m <<= 1)
            s[r] += __shfl_xor(s[r], m, 64);
    }
    if (l16 == 0) {
#pragma unroll
        for (int r = 0; r < 4; ++r)
            out[r0 + wid * 16 + quad * 4 + r] = s[r] + b2v;
    }
}

// ---------- launcher ----------
extern "C" void kernel_launch(void* const* d_in, const int* in_sizes, int n_in,
                              void* d_out, int out_size, void* d_ws, size_t ws_size,
                              hipStream_t stream)
{
    const int*   white = (const int*)d_in[0];
    const int*   black = (const int*)d_in[1];
    const int*   stm   = (const int*)d_in[2];
    const float* emb   = (const float*)d_in[3];
    const float* W1    = (const float*)d_in[4];
    const float* b1    = (const float*)d_in[5];
    const float* W2    = (const float*)d_in[6];
    const float* b2    = (const float*)d_in[7];
    float* out = (float*)d_out;

    unsigned short* xbuf  = (unsigned short*)d_ws;                 // 4096*4096 bf16 = 32 MiB
    unsigned short* w1buf = xbuf + (size_t)4096 * 4096;            // 128*4096 bf16 = 1 MiB

    nnue_gather<<<4096 * 4, 256, 0, stream>>>(white, black, stm, emb, xbuf);
    nnue_convw1<<<512, 256, 0, stream>>>(W1, w1buf);
    nnue_mlp<<<64, 256, 0, stream>>>(xbuf, w1buf, b1, W2, b2, out);
}

// Round 3
// 727.445 us; speedup vs baseline: 1.1383x; 1.1383x over previous
//
#include <hip/hip_runtime.h>
#include <cstddef>

// ---------- helpers ----------
typedef __bf16 bf16x8 __attribute__((ext_vector_type(8)));
typedef float  floatx4 __attribute__((ext_vector_type(4)));

static __device__ __forceinline__ unsigned short f2bf(float f) {
    unsigned int u = __float_as_uint(f);
    u = u + 0x7fff + ((u >> 16) & 1);   // round-to-nearest-even
    return (unsigned short)(u >> 16);
}

// ---------- kernel 1: masked gather-sum -> x (bf16, concat order applied) ----------
// EXACT round-1 code (proven correct, 337 us).
__global__ __launch_bounds__(256) void nnue_gather(
    const int* __restrict__ white, const int* __restrict__ black,
    const int* __restrict__ stm, const float* __restrict__ emb,
    unsigned short* __restrict__ x)
{
    const int blk   = blockIdx.x;
    const int b     = blk >> 2;
    const int piece = blk & 3;
    const int half  = piece >> 1;
    const int sub   = piece & 1;
    const int t     = threadIdx.x;

    __shared__ int sIdx[32];

    const int stm_b = stm[b];
    // half 0 holds (stm? white : black); half 1 holds (stm? black : white)
    const bool use_white = ((stm_b != 0) != (half != 0));
    const int* lst = use_white ? (white + b * 32) : (black + b * 32);
    if (t < 32) sIdx[t] = lst[t];
    __syncthreads();

    const int c = sub * 1024 + t * 4;   // column within the 2048-dim embedding
    float ax = 0.f, ay = 0.f, az = 0.f, aw = 0.f;
#pragma unroll
    for (int l = 0; l < 32; ++l) {
        const int idx = sIdx[l];
        const float4 v = *reinterpret_cast<const float4*>(emb + (size_t)idx * 2048 + c);
        const float m = (idx != 0) ? 1.0f : 0.0f;   // index 0 = padding
        ax += v.x * m; ay += v.y * m; az += v.z * m; aw += v.w * m;
    }
    ushort4 o;
    o.x = f2bf(ax); o.y = f2bf(ay); o.z = f2bf(az); o.w = f2bf(aw);
    *reinterpret_cast<ushort4*>(x + (size_t)b * 4096 + half * 2048 + c) = o;
}

// ---------- kernel 2: W1 fp32 -> bf16 ----------
__global__ __launch_bounds__(256) void nnue_convw1(
    const float* __restrict__ W1, unsigned short* __restrict__ W1b)
{
    const int i = (blockIdx.x * 256 + threadIdx.x) * 4;   // 128*4096 / 4 = 131072 threads
    const float4 v = *reinterpret_cast<const float4*>(W1 + i);
    ushort4 o;
    o.x = f2bf(v.x); o.y = f2bf(v.y); o.z = f2bf(v.z); o.w = f2bf(v.w);
    *reinterpret_cast<ushort4*>(W1b + i) = o;
}

// ---------- kernel 3: fused MLP:  out = relu(x @ W1^T + b1) @ W2^T + b2 ----------
// Minimal delta from the PROVEN round-1 kernel: grid 64->256, BM 64->16.
// All 4 waves share the block's 16 rows; wave w owns N-fragments ni=2w,2w+1
// (full K per wave — NO K-splitting). Staging pattern, fragment reads, MFMA
// call, and C/D handling are identical to round 1. Only the final scalar
// W2-dot partial (per row, per wave) goes through LDS.
#define LDSTRIDE 72   // 64 + 8 bf16 pad
__global__ __launch_bounds__(256) void nnue_mlp(
    const unsigned short* __restrict__ x,   // [4096][4096] bf16
    const unsigned short* __restrict__ w1,  // [128][4096]  bf16
    const float* __restrict__ b1, const float* __restrict__ W2,
    const float* __restrict__ b2, float* __restrict__ out)
{
    __shared__ unsigned short As[16 * LDSTRIDE];
    __shared__ unsigned short Bs[128 * LDSTRIDE];
    __shared__ float red[4 * 16];           // [wave][row] scalar partials

    const int t    = threadIdx.x;
    const int wid  = t >> 6;
    const int lane = t & 63;
    const int quad = lane >> 4;
    const int l16  = lane & 15;
    const int r0   = blockIdx.x * 16;

    floatx4 acc[2];
#pragma unroll
    for (int i = 0; i < 2; ++i) acc[i] = (floatx4){0.f, 0.f, 0.f, 0.f};

    for (int kc = 0; kc < 4096; kc += 64) {
        __syncthreads();
        // stage A: 16 rows x 64 cols bf16 = 128 x 16B chunks (threads 0..127)
        if (t < 128) {
            const int row = t >> 3, cc = t & 7;
            const uint4 v = *reinterpret_cast<const uint4*>(
                x + (size_t)(r0 + row) * 4096 + kc + cc * 8);
            *reinterpret_cast<uint4*>(As + row * LDSTRIDE + cc * 8) = v;
        }
        // stage B (W1): 128 rows x 64 cols = 1024 x 16B chunks
#pragma unroll
        for (int i = 0; i < 4; ++i) {
            const int c = t + i * 256;
            const int row = c >> 3, cc = c & 7;
            const uint4 v = *reinterpret_cast<const uint4*>(
                w1 + (size_t)row * 4096 + kc + cc * 8);
            *reinterpret_cast<uint4*>(Bs + row * LDSTRIDE + cc * 8) = v;
        }
        __syncthreads();
#pragma unroll
        for (int kk = 0; kk < 64; kk += 32) {
            // A frag: A[m = l16][k = kk + quad*8 + j]  (shared by all waves)
            const bf16x8 a = *reinterpret_cast<const bf16x8*>(
                As + l16 * LDSTRIDE + kk + quad * 8);
#pragma unroll
            for (int i = 0; i < 2; ++i) {
                const int ni = wid * 2 + i;
                // B frag: B[k][n = ni*16 + l16] = W1[n][k]
                const bf16x8 bb = *reinterpret_cast<const bf16x8*>(
                    Bs + (ni * 16 + l16) * LDSTRIDE + kk + quad * 8);
                acc[i] = __builtin_amdgcn_mfma_f32_16x16x32_bf16(a, bb, acc[i], 0, 0, 0);
            }
        }
    }

    // epilogue: h = relu(acc + b1); per-wave partial s = h . W2 over its 32 cols
    float s[4] = {0.f, 0.f, 0.f, 0.f};
#pragma unroll
    for (int i = 0; i < 2; ++i) {
        const int col = (wid * 2 + i) * 16 + l16;
        const float bias = b1[col];
        const float w2v  = W2[col];
#pragma unroll
        for (int r = 0; r < 4; ++r) {
            float h = acc[i][r] + bias;
            h = (h > 0.f) ? h : 0.f;
            s[r] += h * w2v;
        }
    }
    // reduce over the 16 l16 lanes of this quad (same as round 1)
#pragma unroll
    for (int r = 0; r < 4; ++r) {
#pragma unroll
        for (int m = 1; m < 16; m <<= 1)
            s[r] += __shfl_xor(s[r], m, 64);
    }
    __syncthreads();   // protect red[] (fresh use of LDS region)
    if (l16 == 0) {
#pragma unroll
        for (int r = 0; r < 4; ++r)
            red[wid * 16 + quad * 4 + r] = s[r];
    }
    __syncthreads();
    if (t < 16)
        out[r0 + t] = red[0 * 16 + t] + red[1 * 16 + t] + red[2 * 16 + t]
                    + red[3 * 16 + t] + b2[0];
}

// ---------- launcher ----------
extern "C" void kernel_launch(void* const* d_in, const int* in_sizes, int n_in,
                              void* d_out, int out_size, void* d_ws, size_t ws_size,
                              hipStream_t stream)
{
    const int*   white = (const int*)d_in[0];
    const int*   black = (const int*)d_in[1];
    const int*   stm   = (const int*)d_in[2];
    const float* emb   = (const float*)d_in[3];
    const float* W1    = (const float*)d_in[4];
    const float* b1    = (const float*)d_in[5];
    const float* W2    = (const float*)d_in[6];
    const float* b2    = (const float*)d_in[7];
    float* out = (float*)d_out;

    unsigned short* xbuf  = (unsigned short*)d_ws;                 // 4096*4096 bf16 = 32 MiB
    unsigned short* w1buf = xbuf + (size_t)4096 * 4096;            // 128*4096 bf16 = 1 MiB

    nnue_gather<<<4096 * 4, 256, 0, stream>>>(white, black, stm, emb, xbuf);
    nnue_convw1<<<512, 256, 0, stream>>>(W1, w1buf);
    nnue_mlp<<<256, 256, 0, stream>>>(xbuf, w1buf, b1, W2, b2, out);
}